// Round 9
// baseline (273.599 us; speedup 1.0000x reference)
//
#include <hip/hip_runtime.h>

// Problem constants (fixed by setup_inputs)
#define NNODES 16384      // B*n = 8*2048
#define KEDGE  16
#define EPS    1e-5f
#define NBLK   1024       // 16 nodes/block; capacity >=4 blocks/CU -> all resident

// Lessons: r2 no same-line atomic RMW storms; r6 no cg::grid.sync (L2 flush);
// r7 no per-block __threadfence (buffer_wbl2 = 3x latency); r8 showed ~80us
// of the 166 is inter-dispatch gaps -> single persistent kernel, flag-synced
// with per-access sc1 atomics (no cache-wide flushes anywhere).

// Workspace layout (floats)
#define PART1_OFF 0                          // 1024 x 128 block partials (BN1)
#define SUBP1_OFF (PART1_OFF + NBLK*128)     // 4 x 128
#define ST1R_OFF  (SUBP1_OFF + 512)          // 64 replicated copies x 128
#define PART2_OFF (ST1R_OFF + 64*128)        // 1024 x 256 block partials (BN2)
#define SUBP2_OFF (PART2_OFF + NBLK*256)     // 4 x 256
#define ST2R_OFF  (SUBP2_OFF + 1024)         // 64 replicated copies x 256
#define CNT_OFF   (ST2R_OFF + 64*256)        // 8 ints (memset-zeroed each call)

#define SCOPE __HIP_MEMORY_SCOPE_AGENT
__device__ __forceinline__ void  ast(float* p, float v) {
    __hip_atomic_store(p, v, __ATOMIC_RELAXED, SCOPE);
}
__device__ __forceinline__ float ald(const float* p) {
    return __hip_atomic_load((float*)p, __ATOMIC_RELAXED, SCOPE);
}
__device__ __forceinline__ int   aldi(const int* p) {
    return __hip_atomic_load((int*)p, __ATOMIC_RELAXED, SCOPE);
}

__global__ __launch_bounds__(256, 4) void k_mega(
    const float* __restrict__ x, const float* __restrict__ p,
    const int* __restrict__ sid, const int* __restrict__ tid,
    const float* __restrict__ W, const float* __restrict__ bias,
    const float* __restrict__ g1, const float* __restrict__ b1,
    const float* __restrict__ W1, const float* __restrict__ bias1,
    const float* __restrict__ W2, const float* __restrict__ bias2,
    const float* __restrict__ g2, const float* __restrict__ b2,
    float* __restrict__ part1, float* __restrict__ subp1,
    float* __restrict__ st1rep, float* __restrict__ part2,
    float* __restrict__ subp2, float* __restrict__ st2rep,
    int* __restrict__ cnt, float* __restrict__ out)
{
    __shared__ float Ash[16][392];        // phase-A staging; reused as scratch
    __shared__ int sh_role, sh_fin;
    float* shf = &Ash[0][0];

    const int lane = threadIdx.x & 63;
    const int wv   = threadIdx.x >> 6;
    const int tw   = blockIdx.x * 16 + wv * 4;   // first node of this wave

    // ======== phase A: edge aggregation + 390x64 GEMM (y1 stays in regs) ====
    const int ii = lane >> 4;
    const int t1 = tw + ii;
    const int s  = sid[t1 * KEDGE + (lane & 15)];     // coalesced
    const int tn1 = tid[t1 * KEDGE];
    const float ptx = p[tn1*3+0], pty = p[tn1*3+1], ptz = p[tn1*3+2];
    const float dx = p[s*3+0] - ptx;
    const float dy = p[s*3+1] - pty;
    const float dz = p[s*3+2] - ptz;
    float pd = fmaxf(sqrtf(dx*dx + dy*dy + dz*dz), 1e-16f);

    float pr = pd;                                     // max over the 16-group
    pr = fmaxf(pr, __shfl_xor(pr, 1));
    pr = fmaxf(pr, __shfl_xor(pr, 2));
    pr = fmaxf(pr, __shfl_xor(pr, 4));
    pr = fmaxf(pr, __shfl_xor(pr, 8));
    pr *= 1.1f;

    float w = (pr - pd) * (pr - pd);
    float wsum = w;
    wsum += __shfl_xor(wsum, 1);
    wsum += __shfl_xor(wsum, 2);
    wsum += __shfl_xor(wsum, 4);
    wsum += __shfl_xor(wsum, 8);
    w /= wsum;

    const float invd = 1.f / pd;
    const float c0 = __cosf(dx * invd);   // |arg|<=1: no range reduction
    const float c1 = __cosf(dy * invd);
    const float c2 = __cosf(dz * invd);
    const float w0 = w * c0 * c0;
    const float w1 = w * c1 * c1;
    const float w2 = w * c2 * c2;
    const int flags = (dx > 0.f ? 1 : 0) | (dy > 0.f ? 2 : 0) | (dz > 0.f ? 4 : 0);

    float xv[4];
    #pragma unroll
    for (int i = 0; i < 4; ++i) {
        const int tn = __shfl(tn1, i * 16);
        const float xt = x[tn*64 + lane];              // lane = channel here
        xv[i] = xt;
        float ev[KEDGE];
        #pragma unroll
        for (int j = 0; j < KEDGE; ++j) {
            const int sv = __shfl(s, i*16 + j);
            ev[j] = x[sv*64 + lane];
        }
        float A0=0,A1=0,A2=0,A3=0,A4=0,A5=0;
        float B0=0,B1=0,B2=0,B3=0,B4=0,B5=0;
        #pragma unroll
        for (int j = 0; j < KEDGE; ++j) {
            const int src = i*16 + j;
            const float q0 = __shfl(w0, src);
            const float q1 = __shfl(w1, src);
            const float q2 = __shfl(w2, src);
            const int   f  = __builtin_amdgcn_readfirstlane(__shfl(flags, src));
            const float e  = ev[j] - xt;
            if (f & 1) { A1 += q0*e; B1 += q0; } else { A0 += q0*e; B0 += q0; }
            if (f & 2) { A3 += q1*e; B3 += q1; } else { A2 += q1*e; B2 += q1; }
            if (f & 4) { A5 += q2*e; B5 += q2; } else { A4 += q2*e; B4 += q2; }
        }
        const int r = wv*4 + i;
        Ash[r][0*64+lane] = A0; Ash[r][1*64+lane] = A1; Ash[r][2*64+lane] = A2;
        Ash[r][3*64+lane] = A3; Ash[r][4*64+lane] = A4; Ash[r][5*64+lane] = A5;
        if (lane == 0) {
            Ash[r][384] = B0; Ash[r][385] = B1; Ash[r][386] = B2;
            Ash[r][387] = B3; Ash[r][388] = B4; Ash[r][389] = B5;
        }
    }
    // Ash rows wave-private; compiler's lgkmcnt wait suffices here.

    const float* Wp = W + lane;
    const int rb = wv * 4;
    float acc[4] = {0,0,0,0};
    #pragma unroll 4
    for (int k = 0; k < 384; k += 4) {
        const float4 a0v = *(const float4*)&Ash[rb+0][k];  // uniform -> bcast
        const float4 a1v = *(const float4*)&Ash[rb+1][k];
        const float4 a2v = *(const float4*)&Ash[rb+2][k];
        const float4 a3v = *(const float4*)&Ash[rb+3][k];
        const float wk0 = Wp[(k+0)*64];
        const float wk1 = Wp[(k+1)*64];
        const float wk2 = Wp[(k+2)*64];
        const float wk3 = Wp[(k+3)*64];
        acc[0] += a0v.x*wk0 + a0v.y*wk1 + a0v.z*wk2 + a0v.w*wk3;
        acc[1] += a1v.x*wk0 + a1v.y*wk1 + a1v.z*wk2 + a1v.w*wk3;
        acc[2] += a2v.x*wk0 + a2v.y*wk1 + a2v.z*wk2 + a2v.w*wk3;
        acc[3] += a3v.x*wk0 + a3v.y*wk1 + a3v.z*wk2 + a3v.w*wk3;
    }
    float bv[6];
    #pragma unroll
    for (int sx = 0; sx < 6; ++sx) bv[sx] = bias[sx*64 + lane];

    float sloc = 0.f, qloc = 0.f;
    #pragma unroll
    for (int i = 0; i < 4; ++i) {
        float a = acc[i];
        #pragma unroll
        for (int sx = 0; sx < 6; ++sx) a += Ash[rb+i][384+sx] * bv[sx];
        acc[i] = a;                         // y1 kept in registers
        sloc += a; qloc += a*a;
    }

    // ---- block BN1 partial: combine 4 waves in LDS, one sc1-store per col
    __syncthreads();                        // all waves done reading Ash
    shf[wv*128 + lane]      = sloc;
    shf[wv*128 + 64 + lane] = qloc;
    __syncthreads();
    if (threadIdx.x < 128)
        ast(&part1[blockIdx.x*128 + threadIdx.x],
            shf[threadIdx.x] + shf[128+threadIdx.x] +
            shf[256+threadIdx.x] + shf[384+threadIdx.x]);
    __syncthreads();                        // barrier drain = release
    if (threadIdx.x == 0) sh_role = atomicAdd(&cnt[0], 1) - (NBLK - 4);
    __syncthreads();

    // ---- last 4 arrivals sub-reduce 256 rows each; 4th combines -> st1rep
    if (sh_role >= 0) {
        const int role = sh_role;
        if (threadIdx.x == 0)
            while (aldi(&cnt[0]) < NBLK) __builtin_amdgcn_s_sleep(1);
        __syncthreads();
        const int c = threadIdx.x & 127, h = threadIdx.x >> 7;
        const float* pp = part1 + ((size_t)role*256 + h*128)*128 + c;
        float sacc = 0.f;
        #pragma unroll 8
        for (int r = 0; r < 128; ++r) sacc += ald(pp + r*128);
        shf[threadIdx.x] = sacc;
        __syncthreads();
        if (threadIdx.x < 128)
            ast(&subp1[role*128 + threadIdx.x],
                shf[threadIdx.x] + shf[128 + threadIdx.x]);
        __syncthreads();                    // drain
        if (threadIdx.x == 0) sh_fin = (atomicAdd(&cnt[1], 1) == 3);
        __syncthreads();
        if (sh_fin) {
            if (threadIdx.x < 128)
                shf[threadIdx.x] =
                    ald(&subp1[threadIdx.x])     + ald(&subp1[128+threadIdx.x]) +
                    ald(&subp1[256+threadIdx.x]) + ald(&subp1[384+threadIdx.x]);
            __syncthreads();
            for (int idx = threadIdx.x; idx < 64*128; idx += 256)
                ast(&st1rep[idx], shf[idx & 127]);
            __syncthreads();                // drain
            if (threadIdx.x == 0)
                __hip_atomic_store(&cnt[2], 1, __ATOMIC_RELAXED, SCOPE);
        }
    }
    if (threadIdx.x == 0)
        while (aldi(&cnt[2]) == 0) __builtin_amdgcn_s_sleep(8);
    __syncthreads();

    // ======== phase B: bn1+relu, dual 64x128 GEMM (t2 stays in regs) ========
    if (threadIdx.x < 128)
        shf[threadIdx.x] = ald(&st1rep[(blockIdx.x & 63)*128 + threadIdx.x]);
    __syncthreads();
    const float n_inv = 1.f / NNODES;
    float zv[4];
    {
        const float mu  = shf[lane] * n_inv;
        const float var = shf[64 + lane] * n_inv - mu*mu;
        const float scv = rsqrtf(var + EPS) * g1[lane];
        const float shv = b1[lane] - mu*scv;
        #pragma unroll
        for (int i = 0; i < 4; ++i) zv[i] = fmaxf(acc[i]*scv + shv, 0.f);
    }
    float a0[4] = {0,0,0,0}, a1[4] = {0,0,0,0};
    #pragma unroll 8
    for (int k = 0; k < 64; ++k) {
        const float w1a = W1[k*128 + lane],      w1b = W1[k*128 + 64 + lane];
        const float w2a = W2[k*128 + lane],      w2b = W2[k*128 + 64 + lane];
        #pragma unroll
        for (int i = 0; i < 4; ++i) {
            const float xk = __shfl(xv[i], k);
            const float zk = __shfl(zv[i], k);
            a0[i] += xk*w1a + zk*w2a;
            a1[i] += xk*w1b + zk*w2b;
        }
    }
    const float bb0 = bias1[lane]      + bias2[lane];
    const float bb1 = bias1[64 + lane] + bias2[64 + lane];
    float s0=0,q0=0,s1=0,q1=0;
    #pragma unroll
    for (int i = 0; i < 4; ++i) {
        a0[i] += bb0; a1[i] += bb1;             // t2 in registers
        s0 += a0[i]; q0 += a0[i]*a0[i];
        s1 += a1[i]; q1 += a1[i]*a1[i];
    }
    __syncthreads();                            // shf (st1 copy) done
    shf[wv*256 + lane]       = s0;
    shf[wv*256 + 64 + lane]  = s1;
    shf[wv*256 + 128 + lane] = q0;
    shf[wv*256 + 192 + lane] = q1;
    __syncthreads();
    ast(&part2[blockIdx.x*256 + threadIdx.x],
        shf[threadIdx.x] + shf[256+threadIdx.x] +
        shf[512+threadIdx.x] + shf[768+threadIdx.x]);
    __syncthreads();                            // drain
    if (threadIdx.x == 0) sh_role = atomicAdd(&cnt[3], 1) - (NBLK - 4);
    __syncthreads();

    if (sh_role >= 0) {
        const int role = sh_role;
        if (threadIdx.x == 0)
            while (aldi(&cnt[3]) < NBLK) __builtin_amdgcn_s_sleep(1);
        __syncthreads();
        const float* pp = part2 + (size_t)role*256*256 + threadIdx.x;
        float sacc = 0.f;
        #pragma unroll 8
        for (int r = 0; r < 256; ++r) sacc += ald(pp + r*256);
        ast(&subp2[role*256 + threadIdx.x], sacc);
        __syncthreads();                        // drain
        if (threadIdx.x == 0) sh_fin = (atomicAdd(&cnt[4], 1) == 3);
        __syncthreads();
        if (sh_fin) {
            shf[threadIdx.x] =
                ald(&subp2[threadIdx.x])     + ald(&subp2[256+threadIdx.x]) +
                ald(&subp2[512+threadIdx.x]) + ald(&subp2[768+threadIdx.x]);
            __syncthreads();
            for (int idx = threadIdx.x; idx < 64*256; idx += 256)
                ast(&st2rep[idx], shf[idx & 255]);
            __syncthreads();                    // drain
            if (threadIdx.x == 0)
                __hip_atomic_store(&cnt[5], 1, __ATOMIC_RELAXED, SCOPE);
        }
    }
    if (threadIdx.x == 0)
        while (aldi(&cnt[5]) == 0) __builtin_amdgcn_s_sleep(8);
    __syncthreads();

    // ======== phase C: bn2+relu straight from registers -> out ==============
    shf[threadIdx.x] = ald(&st2rep[(blockIdx.x & 63)*256 + threadIdx.x]);
    __syncthreads();
    {
        const float mua  = shf[lane] * n_inv;
        const float vara = shf[128 + lane] * n_inv - mua*mua;
        const float sca  = rsqrtf(vara + EPS) * g2[lane];
        const float sha  = b2[lane] - mua*sca;
        const float mub  = shf[64 + lane] * n_inv;
        const float varb = shf[192 + lane] * n_inv - mub*mub;
        const float scb  = rsqrtf(varb + EPS) * g2[64 + lane];
        const float shb  = b2[64 + lane] - mub*scb;
        #pragma unroll
        for (int i = 0; i < 4; ++i) {
            out[(size_t)(tw + i)*128 + lane]      = fmaxf(a0[i]*sca + sha, 0.f);
            out[(size_t)(tw + i)*128 + 64 + lane] = fmaxf(a1[i]*scb + shb, 0.f);
        }
    }
}

extern "C" void kernel_launch(void* const* d_in, const int* in_sizes, int n_in,
                              void* d_out, int out_size, void* d_ws, size_t ws_size,
                              hipStream_t stream)
{
    const float* x     = (const float*)d_in[0];
    const float* p     = (const float*)d_in[1];
    const int*   sid   = (const int*)d_in[2];
    const int*   tid   = (const int*)d_in[3];
    // d_in[4] = B, d_in[5] = n (scalars, unused — constants hardcoded)
    const float* linsW = (const float*)d_in[6];
    const float* linsB = (const float*)d_in[7];
    const float* W1    = (const float*)d_in[8];
    const float* b1l   = (const float*)d_in[9];
    const float* W2    = (const float*)d_in[10];
    const float* b2l   = (const float*)d_in[11];
    const float* g1    = (const float*)d_in[12];
    const float* bb1   = (const float*)d_in[13];
    const float* g2    = (const float*)d_in[14];
    const float* bb2   = (const float*)d_in[15];

    float* ws     = (float*)d_ws;
    float* part1  = ws + PART1_OFF;
    float* subp1  = ws + SUBP1_OFF;
    float* st1rep = ws + ST1R_OFF;
    float* part2  = ws + PART2_OFF;
    float* subp2  = ws + SUBP2_OFF;
    float* st2rep = ws + ST2R_OFF;
    int*   cnts   = (int*)(ws + CNT_OFF);

    hipMemsetAsync(cnts, 0, 8 * sizeof(int), stream);   // phase counters/flags

    k_mega<<<NBLK, 256, 0, stream>>>(x, p, sid, tid, linsW, linsB,
                                     g1, bb1, W1, b1l, W2, b2l, g2, bb2,
                                     part1, subp1, st1rep, part2, subp2, st2rep,
                                     cnts, (float*)d_out);
}

// Round 10
// 158.957 us; speedup vs baseline: 1.7212x; 1.7212x over previous
//
#include <hip/hip_runtime.h>

// Problem constants (fixed by setup_inputs)
#define NNODES 16384      // B*n = 8*2048
#define KEDGE  16
#define EPS    1e-5f

// Lessons: r2 no same-line atomic storms (1M ops/line = 415us);
// r4/r8 best structure but ~80us = 5-6 dispatch boundaries x ~13.5us;
// r6 no cg::grid.sync; r7 no per-block __threadfence (L2 flush);
// r9 no register-carried state across in-kernel global sync (spills).
// r10: 4 graph nodes. BN stats via 8-slot SPREAD atomics (128 ops/addr,
// 32 lines in parallel ~ 2us tail) written by producers, redundantly
// summed by consumers -> both reduction kernels and their boundaries gone.

// Workspace layout (floats)
#define SP1_OFF 0                       // 8 slots x 128 (sum[64], sumsq[64])
#define SP2_OFF (SP1_OFF + 8*128)       // 8 slots x 256
#define Y1_OFF  (SP2_OFF + 8*256)       // y1: 16384*64
#define T2_OFF  (Y1_OFF + NNODES*64)    // t2: 16384*128

// ---------------------------------------------------------------------------
// K1: edge aggregation + 390x64 GEMM + BN1 spread-atomic stats.
// Block = 4 waves x 4 nodes/wave. Per-edge scalars packed in an LDS float4
// table (one uniform ds_read_b128/edge instead of 4 ds_bpermute).
// ---------------------------------------------------------------------------
__global__ __launch_bounds__(256, 4) void k_node(
    const float* __restrict__ x, const float* __restrict__ p,
    const int* __restrict__ sid, const int* __restrict__ tid,
    const float* __restrict__ W, const float* __restrict__ bias,
    float* __restrict__ y1, float* __restrict__ sp1)
{
    __shared__ float  Ash[16][392];    // A rows; 392 keeps rows 16B-aligned
    __shared__ float4 Esh[4][64];      // per-wave edge packets {w0,w1,w2,pack}
    __shared__ float  redsh[512];

    const int lane = threadIdx.x & 63;
    const int wv   = threadIdx.x >> 6;
    const int tw   = blockIdx.x * 16 + wv * 4;   // first node of this wave

    // ---- phase 1: one edge per lane (node ii = lane>>4, edge jj = lane&15)
    const int ii = lane >> 4;
    const int t1 = tw + ii;
    const int s  = sid[t1 * KEDGE + (lane & 15)];     // coalesced
    const int tn1 = tid[t1 * KEDGE];
    const float ptx = p[tn1*3+0], pty = p[tn1*3+1], ptz = p[tn1*3+2];
    const float dx = p[s*3+0] - ptx;
    const float dy = p[s*3+1] - pty;
    const float dz = p[s*3+2] - ptz;
    float pd = fmaxf(sqrtf(dx*dx + dy*dy + dz*dz), 1e-16f);

    float pr = pd;                                     // max over the 16-group
    pr = fmaxf(pr, __shfl_xor(pr, 1));
    pr = fmaxf(pr, __shfl_xor(pr, 2));
    pr = fmaxf(pr, __shfl_xor(pr, 4));
    pr = fmaxf(pr, __shfl_xor(pr, 8));
    pr *= 1.1f;

    float w = (pr - pd) * (pr - pd);
    float wsum = w;
    wsum += __shfl_xor(wsum, 1);
    wsum += __shfl_xor(wsum, 2);
    wsum += __shfl_xor(wsum, 4);
    wsum += __shfl_xor(wsum, 8);
    w /= wsum;

    const float invd = 1.f / pd;
    const float c0 = __cosf(dx * invd);   // |arg|<=1: no range reduction
    const float c1 = __cosf(dy * invd);
    const float c2 = __cosf(dz * invd);
    const int flags = (dx > 0.f ? 1 : 0) | (dy > 0.f ? 2 : 0) | (dz > 0.f ? 4 : 0);
    Esh[wv][lane] = make_float4(w * c0 * c0, w * c1 * c1, w * c2 * c2,
                                __int_as_float((s << 3) | flags));
    // Esh row is wave-private; same-wave lgkmcnt ordering suffices.

    // ---- phase 2: per node, prefetch 16 gathers, then the FMA chain
    #pragma unroll
    for (int i = 0; i < 4; ++i) {
        const int tn = __shfl(tn1, i * 16);
        const float xt = x[tn*64 + lane];              // lane = channel here

        float ev[KEDGE];                               // 16 gathers in flight
        #pragma unroll
        for (int j = 0; j < KEDGE; ++j) {
            const int sv = __shfl(s, i*16 + j);
            ev[j] = x[sv*64 + lane];
        }

        float A0=0,A1=0,A2=0,A3=0,A4=0,A5=0;
        float B0=0,B1=0,B2=0,B3=0,B4=0,B5=0;
        #pragma unroll
        for (int j = 0; j < KEDGE; ++j) {
            const float4 pk = Esh[wv][i*16 + j];       // uniform addr -> bcast
            const int f = __builtin_amdgcn_readfirstlane(__float_as_int(pk.w)) & 7;
            const float e = ev[j] - xt;
            if (f & 1) { A1 += pk.x*e; B1 += pk.x; } else { A0 += pk.x*e; B0 += pk.x; }
            if (f & 2) { A3 += pk.y*e; B3 += pk.y; } else { A2 += pk.y*e; B2 += pk.y; }
            if (f & 4) { A5 += pk.z*e; B5 += pk.z; } else { A4 += pk.z*e; B4 += pk.z; }
        }
        const int r = wv*4 + i;
        Ash[r][0*64+lane] = A0; Ash[r][1*64+lane] = A1; Ash[r][2*64+lane] = A2;
        Ash[r][3*64+lane] = A3; Ash[r][4*64+lane] = A4; Ash[r][5*64+lane] = A5;
        if (lane == 0) {       // B's are lane-invariant
            Ash[r][384] = B0; Ash[r][385] = B1; Ash[r][386] = B2;
            Ash[r][387] = B3; Ash[r][388] = B4; Ash[r][389] = B5;
        }
    }

    // ---- phase 3: 4-row GEMM  y = A @ [lins_W; lins_b]
    const float* Wp = W + lane;
    const int rb = wv * 4;
    float acc[4] = {0,0,0,0};
    #pragma unroll 4
    for (int k = 0; k < 384; k += 4) {
        const float4 a0 = *(const float4*)&Ash[rb+0][k];   // uniform -> bcast
        const float4 a1 = *(const float4*)&Ash[rb+1][k];
        const float4 a2 = *(const float4*)&Ash[rb+2][k];
        const float4 a3 = *(const float4*)&Ash[rb+3][k];
        const float wk0 = Wp[(k+0)*64];
        const float wk1 = Wp[(k+1)*64];
        const float wk2 = Wp[(k+2)*64];
        const float wk3 = Wp[(k+3)*64];
        acc[0] += a0.x*wk0 + a0.y*wk1 + a0.z*wk2 + a0.w*wk3;
        acc[1] += a1.x*wk0 + a1.y*wk1 + a1.z*wk2 + a1.w*wk3;
        acc[2] += a2.x*wk0 + a2.y*wk1 + a2.z*wk2 + a2.w*wk3;
        acc[3] += a3.x*wk0 + a3.y*wk1 + a3.z*wk2 + a3.w*wk3;
    }
    float bv[6];
    #pragma unroll
    for (int sx = 0; sx < 6; ++sx) bv[sx] = bias[sx*64 + lane];

    float sloc = 0.f, qloc = 0.f;
    #pragma unroll
    for (int i = 0; i < 4; ++i) {
        float a = acc[i];
        #pragma unroll
        for (int sx = 0; sx < 6; ++sx) a += Ash[rb+i][384+sx] * bv[sx];
        y1[(tw+i)*64 + lane] = a;
        sloc += a; qloc += a*a;
    }

    // ---- BN1 stats: block LDS combine -> one atomicAdd/channel into slot
    __syncthreads();                       // all waves done with Ash
    redsh[wv*128 + lane]      = sloc;
    redsh[wv*128 + 64 + lane] = qloc;
    __syncthreads();
    if (threadIdx.x < 128) {
        const int t = threadIdx.x;
        const float v = redsh[t] + redsh[128+t] + redsh[256+t] + redsh[384+t];
        atomicAdd(&sp1[(blockIdx.x & 7)*128 + t], v);   // 128 blocks/addr
    }
}

// ---------------------------------------------------------------------------
// K2: t2 = x@lin1_W + relu(bn1(y1))@lin2_W + biases; BN1 stats summed
// redundantly from the 8 spread slots; BN2 stats via spread atomics.
// One wave = 4 rows; lane covers output cols {lane, lane+64}.
// ---------------------------------------------------------------------------
__global__ __launch_bounds__(256, 4) void k_fused2(
    const float* __restrict__ x, const int* __restrict__ tid,
    const float* __restrict__ y1, const float* __restrict__ sp1,
    const float* __restrict__ g1, const float* __restrict__ b1,
    const float* __restrict__ W1, const float* __restrict__ bias1,
    const float* __restrict__ W2, const float* __restrict__ bias2,
    float* __restrict__ t2, float* __restrict__ sp2)
{
    __shared__ float st1sh[128];
    __shared__ float redsh[1024];

    const int lane = threadIdx.x & 63;
    const int wv   = threadIdx.x >> 6;
    const int r0   = (blockIdx.x * 4 + wv) * 4;

    if (threadIdx.x < 128) {               // redundant 8-slot sum (4 KB of L2)
        float v = 0.f;
        #pragma unroll
        for (int s8 = 0; s8 < 8; ++s8) v += sp1[s8*128 + threadIdx.x];
        st1sh[threadIdx.x] = v;
    }
    __syncthreads();

    const float n_inv = 1.f / NNODES;
    const float mu  = st1sh[lane] * n_inv;
    const float var = st1sh[64 + lane] * n_inv - mu*mu;
    const float sc  = rsqrtf(var + EPS) * g1[lane];
    const float sh  = b1[lane] - mu*sc;

    float xv[4], zv[4];
    #pragma unroll
    for (int i = 0; i < 4; ++i) {
        const int tn = tid[(r0 + i) * KEDGE];
        xv[i] = x[tn*64 + lane];
        const float yv = y1[(r0 + i)*64 + lane];
        zv[i] = fmaxf(yv*sc + sh, 0.f);
    }
    float a0[4] = {0,0,0,0}, a1[4] = {0,0,0,0};
    #pragma unroll 8
    for (int k = 0; k < 64; ++k) {
        const float w1a = W1[k*128 + lane],      w1b = W1[k*128 + 64 + lane];
        const float w2a = W2[k*128 + lane],      w2b = W2[k*128 + 64 + lane];
        #pragma unroll
        for (int i = 0; i < 4; ++i) {
            const float xk = __shfl(xv[i], k);
            const float zk = __shfl(zv[i], k);
            a0[i] += xk*w1a + zk*w2a;
            a1[i] += xk*w1b + zk*w2b;
        }
    }
    const float bb0 = bias1[lane]      + bias2[lane];
    const float bb1 = bias1[64 + lane] + bias2[64 + lane];
    float s0=0,q0=0,s1=0,q1=0;
    #pragma unroll
    for (int i = 0; i < 4; ++i) {
        const float v0 = a0[i] + bb0;
        const float v1 = a1[i] + bb1;
        t2[(size_t)(r0 + i)*128 + lane]      = v0;
        t2[(size_t)(r0 + i)*128 + 64 + lane] = v1;
        s0 += v0; q0 += v0*v0;
        s1 += v1; q1 += v1*v1;
    }
    // BN2 stats: block LDS combine -> one atomicAdd/column into slot
    redsh[wv*256 + lane]       = s0;   // sum   cols 0..63
    redsh[wv*256 + 64 + lane]  = s1;   // sum   cols 64..127
    redsh[wv*256 + 128 + lane] = q0;   // sumsq cols 0..63
    redsh[wv*256 + 192 + lane] = q1;   // sumsq cols 64..127
    __syncthreads();
    {
        const int t = threadIdx.x;
        const float v = redsh[t] + redsh[256+t] + redsh[512+t] + redsh[768+t];
        atomicAdd(&sp2[(blockIdx.x & 7)*256 + t], v);   // 128 blocks/addr
    }
}

// ---------------------------------------------------------------------------
// K3: out = relu(bn2(t2)); st2 summed redundantly from the 8 spread slots;
// float4-vectorized (memory-bound, ~16 MB r/w).
// ---------------------------------------------------------------------------
__global__ __launch_bounds__(256) void k_bn2(
    const float* __restrict__ t2, const float* __restrict__ sp2,
    const float* __restrict__ g2, const float* __restrict__ b2,
    float* __restrict__ out)
{
    __shared__ float st2sh[256];
    {
        float v = 0.f;
        #pragma unroll
        for (int s8 = 0; s8 < 8; ++s8) v += sp2[s8*256 + threadIdx.x];
        st2sh[threadIdx.x] = v;            // [0..127]=sum ch, [128..255]=sumsq ch
    }
    __syncthreads();

    const int i4 = blockIdx.x * 256 + threadIdx.x;   // float4 index
    const int c4 = i4 & 31;                          // float4 within 128 cols
    const float4 sum4 = ((const float4*)st2sh)[c4];
    const float4 sq4  = ((const float4*)(st2sh + 128))[c4];
    const float4 g4   = ((const float4*)g2)[c4];
    const float4 bb4  = ((const float4*)b2)[c4];
    const float4 v    = ((const float4*)t2)[i4];
    const float n_inv = 1.f / NNODES;
    float4 o;
    {
        const float m = sum4.x*n_inv, va = sq4.x*n_inv - m*m;
        const float scv = rsqrtf(va + EPS)*g4.x;
        o.x = fmaxf(v.x*scv + (bb4.x - m*scv), 0.f);
    }
    {
        const float m = sum4.y*n_inv, va = sq4.y*n_inv - m*m;
        const float scv = rsqrtf(va + EPS)*g4.y;
        o.y = fmaxf(v.y*scv + (bb4.y - m*scv), 0.f);
    }
    {
        const float m = sum4.z*n_inv, va = sq4.z*n_inv - m*m;
        const float scv = rsqrtf(va + EPS)*g4.z;
        o.z = fmaxf(v.z*scv + (bb4.z - m*scv), 0.f);
    }
    {
        const float m = sum4.w*n_inv, va = sq4.w*n_inv - m*m;
        const float scv = rsqrtf(va + EPS)*g4.w;
        o.w = fmaxf(v.w*scv + (bb4.w - m*scv), 0.f);
    }
    ((float4*)out)[i4] = o;
}

extern "C" void kernel_launch(void* const* d_in, const int* in_sizes, int n_in,
                              void* d_out, int out_size, void* d_ws, size_t ws_size,
                              hipStream_t stream)
{
    const float* x     = (const float*)d_in[0];
    const float* p     = (const float*)d_in[1];
    const int*   sid   = (const int*)d_in[2];
    const int*   tid   = (const int*)d_in[3];
    // d_in[4] = B, d_in[5] = n (scalars, unused — constants hardcoded)
    const float* linsW = (const float*)d_in[6];
    const float* linsB = (const float*)d_in[7];
    const float* W1    = (const float*)d_in[8];
    const float* b1l   = (const float*)d_in[9];
    const float* W2    = (const float*)d_in[10];
    const float* b2l   = (const float*)d_in[11];
    const float* g1    = (const float*)d_in[12];
    const float* bb1   = (const float*)d_in[13];
    const float* g2    = (const float*)d_in[14];
    const float* bb2   = (const float*)d_in[15];

    float* ws  = (float*)d_ws;
    float* sp1 = ws + SP1_OFF;
    float* sp2 = ws + SP2_OFF;
    float* y1  = ws + Y1_OFF;
    float* t2  = ws + T2_OFF;

    // zero the 8-slot spread accumulators (12 KB)
    hipMemsetAsync(sp1, 0, (8*128 + 8*256) * sizeof(float), stream);

    k_node  <<<NNODES/16,            256, 0, stream>>>(x, p, sid, tid, linsW,
                                                       linsB, y1, sp1);
    k_fused2<<<NNODES/16,            256, 0, stream>>>(x, tid, y1, sp1, g1, bb1,
                                                       W1, b1l, W2, b2l, t2, sp2);
    k_bn2   <<<(NNODES*128)/(256*4), 256, 0, stream>>>(t2, sp2, g2, bb2,
                                                       (float*)d_out);
}